// Round 1
// baseline (1238.979 us; speedup 1.0000x reference)
//
#include <hip/hip_runtime.h>
#include <stdint.h>

// ---------------------------------------------------------------------------
// ColorExtractor: per-image k-means (B=64, N=224*224, C=3, K=16, 10 iters).
// Output depends on jax.random.permutation(key_b, N)[:16] -> must reproduce
// JAX threefry2x32 bit-exactly. JAX_PARTITIONABLE=1 models modern JAX
// (jax_threefry_partitionable default True, >=0.4.36). Set to 0 for the
// legacy split-half-counter generation if this round mismatches.
// ---------------------------------------------------------------------------

#ifndef JAX_PARTITIONABLE
#define JAX_PARTITIONABLE 1
#endif

#define NB    64
#define NPIX  50176
#define NK    16
#define NCH   3
#define NITER 10

struct KeyPair { uint32_t a, b; };

__device__ __forceinline__ uint32_t rotl32(uint32_t v, uint32_t r) {
  return (v << r) | (v >> (32u - r));
}

__device__ __forceinline__ void tf_round(uint32_t& x0, uint32_t& x1, uint32_t r) {
  x0 += x1; x1 = rotl32(x1, r); x1 ^= x0;
}

// Threefry-2x32, 20 rounds, exactly as jax/_src/prng.py lowering.
__device__ __forceinline__ KeyPair threefry(uint32_t k0, uint32_t k1,
                                            uint32_t x0, uint32_t x1) {
  const uint32_t ks2 = k0 ^ k1 ^ 0x1BD11BDAu;
  x0 += k0; x1 += k1;
  tf_round(x0, x1, 13u); tf_round(x0, x1, 15u); tf_round(x0, x1, 26u); tf_round(x0, x1, 6u);
  x0 += k1;  x1 += ks2 + 1u;
  tf_round(x0, x1, 17u); tf_round(x0, x1, 29u); tf_round(x0, x1, 16u); tf_round(x0, x1, 24u);
  x0 += ks2; x1 += k0 + 2u;
  tf_round(x0, x1, 13u); tf_round(x0, x1, 15u); tf_round(x0, x1, 26u); tf_round(x0, x1, 6u);
  x0 += k0;  x1 += k1 + 3u;
  tf_round(x0, x1, 17u); tf_round(x0, x1, 29u); tf_round(x0, x1, 16u); tf_round(x0, x1, 24u);
  x0 += k1;  x1 += ks2 + 4u;
  tf_round(x0, x1, 13u); tf_round(x0, x1, 15u); tf_round(x0, x1, 26u); tf_round(x0, x1, 6u);
  x0 += ks2; x1 += k0 + 5u;
  KeyPair r; r.a = x0; r.b = x1; return r;
}

// sort_keys[i] for _random_bits(subkey, 32, (NPIX,)).
__device__ __forceinline__ uint32_t sortkey(KeyPair S, uint32_t i) {
#if JAX_PARTITIONABLE
  KeyPair r = threefry(S.a, S.b, 0u, i);     // counter = 64-bit iota (hi=0, lo=i)
  return r.a ^ r.b;                          // 32-bit path XOR-folds the block
#else
  const uint32_t half = NPIX / 2u;           // original: counts split into halves
  if (i < half) return threefry(S.a, S.b, i, half + i).a;
  return threefry(S.a, S.b, i - half, i).b;
#endif
}

// key_b = split(key(42), 64)[b]; then round-1/2 subkeys of _shuffle.
__device__ __forceinline__ void derive_keys(int b, KeyPair& S1, KeyPair& S2) {
#if JAX_PARTITIONABLE
  KeyPair root; root.a = 0u; root.b = 42u;
  KeyPair kb = threefry(root.a, root.b, 0u, (uint32_t)b);   // foldlike split
  KeyPair K1 = threefry(kb.a, kb.b, 0u, 0u);                // key after round-1 split
  S1 = threefry(kb.a, kb.b, 0u, 1u);                        // round-1 subkey
  S2 = threefry(K1.a, K1.b, 0u, 1u);                        // round-2 subkey
#else
  KeyPair root; root.a = 0u; root.b = 42u;
  KeyPair kb;
  if (b < 32) {  // out = concat(y0, y1) of counts arange(128) split in halves
    kb.a = threefry(root.a, root.b, (uint32_t)(2 * b),     (uint32_t)(64 + 2 * b)).a;
    kb.b = threefry(root.a, root.b, (uint32_t)(2 * b + 1), (uint32_t)(65 + 2 * b)).a;
  } else {
    kb.a = threefry(root.a, root.b, (uint32_t)(2 * b - 64), (uint32_t)(2 * b)).b;
    kb.b = threefry(root.a, root.b, (uint32_t)(2 * b - 63), (uint32_t)(2 * b + 1)).b;
  }
  KeyPair p0 = threefry(kb.a, kb.b, 0u, 2u);
  KeyPair p1 = threefry(kb.a, kb.b, 1u, 3u);
  KeyPair K1; K1.a = p0.a; K1.b = p1.a;
  S1.a = p0.b; S1.b = p1.b;
  KeyPair q0 = threefry(K1.a, K1.b, 0u, 2u);
  KeyPair q1 = threefry(K1.a, K1.b, 1u, 3u);
  S2.a = q0.b; S2.b = q1.b;
#endif
}

// ---------------------------------------------------------------------------
// kinit: one block per batch. Computes perm[:16] = s1(s2(p)) without a full
// sort, gathers initial centroids, zeroes sums.
//   Phase A: 16 smallest (keys2[i], i)   -> target ranks R_p = s2(p)
//   Phase B: index at stable-rank R_p under keys1 (11-bit prefix histogram)
// ---------------------------------------------------------------------------
__global__ __launch_bounds__(256) void kinit(const float* __restrict__ x,
                                             float* __restrict__ cent,
                                             float* __restrict__ sums) {
  const int b = (int)blockIdx.x;
  const int tid = (int)threadIdx.x;

  __shared__ unsigned long long cand[2048];      // (key2<<32)|idx candidates
  __shared__ unsigned long long coll[NK][128];   // per-target (key1<<32)|idx
  __shared__ uint32_t hist[2048];                // keys1 top-11-bit histogram
  __shared__ uint32_t Rtgt[NK];                  // s2(p), p=0..15
  __shared__ uint32_t binsel[NK];
  __shared__ uint32_t rem[NK];
  __shared__ int jsel[NK];
  __shared__ int ncand;
  __shared__ int ncoll[NK];

  KeyPair S1, S2;
  derive_keys(b, S1, S2);

  if (tid == 0) ncand = 0;
  if (tid < NK) ncoll[tid] = 0;
  for (int i = tid; i < 2048; i += 256) hist[i] = 0u;
  __syncthreads();

  const uint32_t T2 = 27394240u;  // ~2^32*320/NPIX: expect ~320 candidates

  // Pass 1: keys2 candidate filter + keys1 prefix histogram
  for (int i = tid; i < NPIX; i += 256) {
    uint32_t k2 = sortkey(S2, (uint32_t)i);
    if (k2 < T2) {
      int p = atomicAdd(&ncand, 1);
      if (p < 2048) cand[p] = ((unsigned long long)k2 << 32) | (uint32_t)i;
    }
    uint32_t k1 = sortkey(S1, (uint32_t)i);
    atomicAdd(&hist[k1 >> 21], 1u);
  }
  __syncthreads();

  // Rank candidates (distinct (key,idx) pairs -> unique ranks); keep top-16.
  const int M = ncand < 2048 ? ncand : 2048;
  for (int j = tid; j < M; j += 256) {
    unsigned long long me = cand[j];
    int rank = 0;
    for (int t = 0; t < M; ++t) rank += (cand[t] < me) ? 1 : 0;
    if (rank < NK) Rtgt[rank] = (uint32_t)(me & 0xffffffffu);
  }
  __syncthreads();

  // Locate each target rank's 11-bit prefix bin and residual rank.
  if (tid < NK) {
    uint32_t R = Rtgt[tid];
    uint32_t cum = 0u, bin = 0u;
    for (int i = 0; i < 2048; ++i) {
      uint32_t h = hist[i];
      if (R < cum + h) { bin = (uint32_t)i; break; }
      cum += h;
    }
    binsel[tid] = bin;
    rem[tid] = R - cum;
  }
  __syncthreads();

  // Pass 2: collect keys1 elements landing in each target's bin.
  for (int i = tid; i < NPIX; i += 256) {
    uint32_t k1 = sortkey(S1, (uint32_t)i);
    uint32_t pb = k1 >> 21;
    #pragma unroll
    for (int t = 0; t < NK; ++t) {
      if (pb == binsel[t]) {
        int p = atomicAdd(&ncoll[t], 1);
        if (p < 128) coll[t][p] = ((unsigned long long)k1 << 32) | (uint32_t)i;
      }
    }
  }
  __syncthreads();

  // Stable selection: rem-th smallest (key, idx) lexicographically.
  if (tid < NK) {
    int m = ncoll[tid] < 128 ? ncoll[tid] : 128;
    uint32_t r = rem[tid];
    unsigned long long lo = 0ULL;
    unsigned long long cur = ~0ULL;
    bool first = true;
    for (uint32_t pass = 0; pass <= r; ++pass) {
      cur = ~0ULL;
      for (int t = 0; t < m; ++t) {
        unsigned long long v = coll[tid][t];
        if ((first || v > lo) && v < cur) cur = v;
      }
      lo = cur; first = false;
    }
    jsel[tid] = (int)(cur & 0xffffffffu);
  }
  __syncthreads();

  if (tid < NK * NCH) {
    int k = tid / NCH, c = tid % NCH;
    int j = jsel[k];
    cent[(b * NK + k) * NCH + c] = x[((size_t)b * NPIX + (size_t)j) * NCH + c];
  }
  if (tid < NK * 4) sums[b * NK * 4 + tid] = 0.0f;
}

// ---------------------------------------------------------------------------
// kassign: assignment + accumulation. grid = (chunks, B).
// Arithmetic matches numpy exactly (_rn intrinsics forbid fma contraction);
// tie-break = first minimal k (ascending scan, strict <); first NaN wins
// like np.argmin (only reachable if a cluster goes empty).
// ---------------------------------------------------------------------------
__global__ __launch_bounds__(256) void kassign(const float* __restrict__ x,
                                               const float* __restrict__ cent,
                                               float* __restrict__ sums) {
  const int b = (int)blockIdx.y;
  const int tid = (int)threadIdx.x;
  __shared__ float cs[NK * NCH];
  __shared__ float acc[NK * 4];
  if (tid < NK * NCH) cs[tid] = cent[b * NK * NCH + tid];
  if (tid < NK * 4) acc[tid] = 0.0f;
  __syncthreads();

  const int per = (NPIX + (int)gridDim.x - 1) / (int)gridDim.x;
  const int start = (int)blockIdx.x * per;
  const int end = (start + per < NPIX) ? (start + per) : NPIX;
  const float* xb = x + (size_t)b * NPIX * NCH;

  for (int p = start + tid; p < end; p += 256) {
    const float v0 = xb[3 * p + 0];
    const float v1 = xb[3 * p + 1];
    const float v2 = xb[3 * p + 2];
    int best = 0;
    float bd = 3.402823466e38f;
    #pragma unroll
    for (int k = 0; k < NK; ++k) {
      float d0 = __fsub_rn(v0, cs[k * 3 + 0]);
      float d1 = __fsub_rn(v1, cs[k * 3 + 1]);
      float d2 = __fsub_rn(v2, cs[k * 3 + 2]);
      float d = __fadd_rn(__fadd_rn(__fmul_rn(d0, d0), __fmul_rn(d1, d1)),
                          __fmul_rn(d2, d2));
      if (d != d) { best = k; break; }       // np.argmin: first NaN wins
      if (d < bd) { bd = d; best = k; }
    }
    atomicAdd(&acc[best * 4 + 0], v0);
    atomicAdd(&acc[best * 4 + 1], v1);
    atomicAdd(&acc[best * 4 + 2], v2);
    atomicAdd(&acc[best * 4 + 3], 1.0f);
  }
  __syncthreads();
  if (tid < NK * 4) atomicAdd(&sums[b * NK * 4 + tid], acc[tid]);
}

// ---------------------------------------------------------------------------
// kupdate: cent = sums/counts (0/0 -> NaN, matching the reference), write
// d_out (last iteration's values persist), re-zero sums for next iteration.
// ---------------------------------------------------------------------------
__global__ __launch_bounds__(64) void kupdate(float* __restrict__ cent,
                                              float* __restrict__ sums,
                                              float* __restrict__ out) {
  const int b = (int)blockIdx.x;
  const int t = (int)threadIdx.x;
  float v = 0.0f;
  if (t < NK * NCH) {
    const int k = t / NCH, c = t % NCH;
    const float s = sums[b * NK * 4 + k * 4 + c];
    const float cnt = sums[b * NK * 4 + k * 4 + 3];
    v = s / cnt;
  }
  __syncthreads();  // reads of sums complete before re-zeroing
  if (t < NK * NCH) {
    cent[b * NK * NCH + t] = v;
    out[b * NK * NCH + t] = v;
  }
  sums[b * NK * 4 + t] = 0.0f;
}

extern "C" void kernel_launch(void* const* d_in, const int* in_sizes, int n_in,
                              void* d_out, int out_size, void* d_ws, size_t ws_size,
                              hipStream_t stream) {
  (void)in_sizes; (void)n_in; (void)out_size; (void)ws_size;
  const float* x = (const float*)d_in[0];
  float* out = (float*)d_out;
  float* cent = (float*)d_ws;                  // NB*NK*NCH floats
  float* sums = cent + NB * NK * NCH;          // NB*NK*4  floats

  kinit<<<NB, 256, 0, stream>>>(x, cent, sums);
  for (int it = 0; it < NITER; ++it) {
    kassign<<<dim3(64, NB), 256, 0, stream>>>(x, cent, sums);
    kupdate<<<NB, 64, 0, stream>>>(cent, sums, out);
  }
}